// Round 2
// baseline (37.095 us; speedup 1.0000x reference)
//
#include <hip/hip_runtime.h>
#include <float.h>

// Problem constants
#define NB 8
#define NC 64
#define NH 32
#define NW 32
#define NQ 8
#define NK 256
#define NROWS (NB*NC*NH*NW)      // 524288 rows, one per (b,c,h,w)
#define TPB 256
#define NBLK (NROWS/TPB)         // 2048
#define BIT_OFF 1
#define REC_OFF (1 + NROWS*NQ)   // 1 + 4194304

// Each block covers 256 consecutive gids = one (b,c), hw-range of 256.
// dist_k(row) = s_row + c2[k] - 2*(x*A[c][k] + B[c][k]);  s_row constant per row
//   => argmin_k of  P[k] + x*S[k],  P = c2-2B, S = -2A   (1 f64 FMA per code)
// bit_out(row) = codebook[best]  (straight-through == out exactly)
// recon(row)   = R[c][best],  R = sum_q cb[k][q]*w_after[c][q] + b_after[c]
// kl row-sum   = full dist[best] = bd + x^2*sw2 + 2x*swb + sb2
__global__ __launch_bounds__(TPB) void vq_main(
    const float* __restrict__ x,
    const float* __restrict__ w_pre,
    const float* __restrict__ b_pre,
    const float* __restrict__ codebook,
    const float* __restrict__ w_after,
    const float* __restrict__ b_after,
    float* __restrict__ out,
    double* __restrict__ partial)
{
    __shared__ double2 s_PS[NK];      // {P[k], S[k]}
    __shared__ double  s_R[NK];       // recon value per code (this block's c)
    __shared__ float   s_cb[NK][NQ];  // raw codebook rows (f32 copy)
    __shared__ double  s_part[TPB/64];

    const int tid = threadIdx.x;
    const int gid = blockIdx.x * TPB + tid;
    const int c  = (gid >> 10) & 63;   // block-uniform
    const int b  = gid >> 16;          // block-uniform
    const int hw = gid & 1023;

    // Per-channel weights (block-uniform -> scalar loads)
    double wp[NQ], bp[NQ], wa[NQ];
    #pragma unroll
    for (int q = 0; q < NQ; q++) {
        wp[q] = (double)w_pre[c*NQ + q];
        bp[q] = (double)b_pre[c*NQ + q];
        wa[q] = (double)w_after[c*NQ + q];
    }
    const double ba = (double)b_after[c];

    // Stage per-code tables; thread tid handles code k = tid
    {
        const int k = tid;
        double c2 = 0.0, A = 0.0, Bv = 0.0, R = ba;
        #pragma unroll
        for (int q = 0; q < NQ; q++) {
            float cf = codebook[k*NQ + q];
            s_cb[k][q] = cf;
            double cv = (double)cf;
            c2 = fma(cv, cv, c2);
            A  = fma(wp[q], cv, A);
            Bv = fma(bp[q], cv, Bv);
            R  = fma(wa[q], cv, R);
        }
        s_PS[k] = make_double2(c2 - 2.0*Bv, -2.0*A);
        s_R[k]  = R;
    }
    __syncthreads();

    const double xv = (double)x[gid];

    // ---- argmin scan: d = P[k] + x*S[k], strict < keeps first occurrence ----
    int best = 0;
    double bd = DBL_MAX;
    #pragma unroll 8
    for (int k = 0; k < NK; k++) {
        double2 ps = s_PS[k];           // wave-uniform LDS broadcast
        double d = fma(xv, ps.y, ps.x);
        if (d < bd) { bd = d; best = k; }
    }

    // ---- outputs ----
    const int bq_base = BIT_OFF + (b*512 + c*8)*1024 + hw;
    #pragma unroll
    for (int q = 0; q < NQ; q++)
        out[bq_base + q*1024] = s_cb[best][q];   // bit_out == codebook[best]
    out[REC_OFF + gid] = (float)s_R[best];

    // ---- kl partial: full dist = bd + (x^2*sw2 + 2x*swb + sb2) ----
    double sw2 = 0.0, swb = 0.0, sb2 = 0.0;
    #pragma unroll
    for (int q = 0; q < NQ; q++) {
        sw2 = fma(wp[q], wp[q], sw2);
        swb = fma(wp[q], bp[q], swb);
        sb2 = fma(bp[q], bp[q], sb2);
    }
    double ksum = bd + fma(xv, fma(xv, sw2, 2.0*swb), sb2);

    #pragma unroll
    for (int off = 32; off; off >>= 1)
        ksum += __shfl_down(ksum, off, 64);
    if ((tid & 63) == 0) s_part[tid >> 6] = ksum;
    __syncthreads();
    if (tid == 0)
        partial[blockIdx.x] = s_part[0] + s_part[1] + s_part[2] + s_part[3];
}

__global__ __launch_bounds__(TPB) void vq_fin(
    const double* __restrict__ partial,
    float* __restrict__ out)
{
    double s = 0.0;
    for (int i = threadIdx.x; i < NBLK; i += TPB) s += partial[i];
    #pragma unroll
    for (int off = 32; off; off >>= 1)
        s += __shfl_down(s, off, 64);
    __shared__ double sp[TPB/64];
    if ((threadIdx.x & 63) == 0) sp[threadIdx.x >> 6] = s;
    __syncthreads();
    if (threadIdx.x == 0) {
        double m = (sp[0] + sp[1] + sp[2] + sp[3]) / (double)(NROWS * NQ);
        out[0] = (float)(1.25 * m);   // mean(diff^2) + 0.25*mean(diff^2)
    }
}

extern "C" void kernel_launch(void* const* d_in, const int* in_sizes, int n_in,
                              void* d_out, int out_size, void* d_ws, size_t ws_size,
                              hipStream_t stream) {
    const float* x        = (const float*)d_in[0];
    const float* w_pre    = (const float*)d_in[1];
    const float* b_pre    = (const float*)d_in[2];
    const float* codebook = (const float*)d_in[3];
    const float* w_after  = (const float*)d_in[4];
    const float* b_after  = (const float*)d_in[5];
    float* out = (float*)d_out;
    double* partial = (double*)d_ws;   // 2048 doubles = 16 KiB scratch

    vq_main<<<NBLK, TPB, 0, stream>>>(x, w_pre, b_pre, codebook, w_after, b_after,
                                      out, partial);
    vq_fin<<<1, TPB, 0, stream>>>(partial, out);
}

// Round 3
// 33.511 us; speedup vs baseline: 1.1070x; 1.1070x over previous
//
#include <hip/hip_runtime.h>
#include <float.h>

// Problem constants
#define NB 8
#define NC 64
#define NH 32
#define NW 32
#define NQ 8
#define NK 256
#define NROWS (NB*NC*NH*NW)      // 524288 rows, one per (b,c,h,w)
#define TPB 256
#define NBLK (NROWS/TPB)         // 2048
#define BIT_OFF 1
#define REC_OFF (1 + NROWS*NQ)   // 1 + 4194304

// d_ws layout:
//   [0,       128K): double breaks[64][256]   (breaks[c][i] = start of segment i, i>=1)
//   [128K,    192K): int    winners[64][256]
//   [192K, 192K+256): int   mcnt[64]
//   [256K, 256K+16K): double partial[2048]
#define WS_BREAKS(ws)  ((double*)(ws))
#define WS_WIN(ws)     ((int*)((char*)(ws) + 131072))
#define WS_M(ws)       ((int*)((char*)(ws) + 196608))
#define WS_PART(ws)    ((double*)((char*)(ws) + 262144))

// ---------------------------------------------------------------------------
// Kernel 1: per-channel lower envelope of the 256 lines d_k(x) = P[k] + x*S[k]
//   P[k] = c2[k] - 2*sum_q b_pre[c][q]*cb[k][q],  S[k] = -2*sum_q w_pre[c][q]*cb[k][q]
// Winner at x=-inf is argmax S (tie: min P, then min k). Walk crossings in
// increasing x: next line = argmin over {j: S_j < S_i} of x* = (P_j-P_i)/(S_i-S_j)
// (tie: min S_j, then min j). All f64 => matches the exact-math argmin that the
// previous (passing) full-scan kernel computed, up to ~1e-16 boundary rounding.
// ---------------------------------------------------------------------------
__global__ __launch_bounds__(TPB) void vq_envelope(
    const float* __restrict__ w_pre,
    const float* __restrict__ b_pre,
    const float* __restrict__ codebook,
    double* __restrict__ g_breaks,
    int* __restrict__ g_win,
    int* __restrict__ g_m)
{
    __shared__ double s_P[NK], s_S[NK];
    __shared__ double s_rx[4], s_rs[4];
    __shared__ int    s_rj[4];
    __shared__ double s_bx;
    __shared__ int    s_bj;

    const int c = blockIdx.x;
    const int k = threadIdx.x;

    // P[k], S[k] for this channel
    {
        double A = 0.0, Bv = 0.0, c2 = 0.0;
        #pragma unroll
        for (int q = 0; q < NQ; q++) {
            double wv = (double)w_pre[c*NQ + q];
            double bv = (double)b_pre[c*NQ + q];
            double cv = (double)codebook[k*NQ + q];
            c2 = fma(cv, cv, c2);
            A  = fma(wv, cv, A);
            Bv = fma(bv, cv, Bv);
        }
        s_P[k] = c2 - 2.0*Bv;
        s_S[k] = -2.0*A;
    }
    __syncthreads();

    // initial winner at x = -inf: max S, tie min P, tie min k
    {
        double bs = s_S[k], bp = s_P[k];
        int bj = k;
        #pragma unroll
        for (int off = 32; off; off >>= 1) {
            double os = __shfl_down(bs, off, 64);
            double op = __shfl_down(bp, off, 64);
            int    oj = __shfl_down(bj, off, 64);
            if (os > bs || (os == bs && (op < bp || (op == bp && oj < bj)))) {
                bs = os; bp = op; bj = oj;
            }
        }
        if ((k & 63) == 0) { s_rx[k>>6] = bs; s_rs[k>>6] = bp; s_rj[k>>6] = bj; }
        __syncthreads();
        if (k == 0) {
            bs = s_rx[0]; bp = s_rs[0]; bj = s_rj[0];
            for (int i = 1; i < 4; i++) {
                if (s_rx[i] > bs || (s_rx[i] == bs && (s_rs[i] < bp ||
                    (s_rs[i] == bp && s_rj[i] < bj)))) {
                    bs = s_rx[i]; bp = s_rs[i]; bj = s_rj[i];
                }
            }
            s_bj = bj;
        }
        __syncthreads();
    }
    int cur = s_bj;
    if (k == 0) g_win[c*NK + 0] = cur;
    int m = 1;

    while (m < NK) {
        const double Si = s_S[cur], Pi = s_P[cur];
        const double Sj = s_S[k],  Pj = s_P[k];
        double cx = DBL_MAX, cs = 0.0;
        int cj = NK;
        if (Sj < Si) {                       // j can overtake i at some x*
            cx = (Pj - Pi) / (Si - Sj);
            cs = Sj; cj = k;
        }
        // block argmin over (cx, cs, cj)
        #pragma unroll
        for (int off = 32; off; off >>= 1) {
            double ox = __shfl_down(cx, off, 64);
            double os = __shfl_down(cs, off, 64);
            int    oj = __shfl_down(cj, off, 64);
            if (ox < cx || (ox == cx && (os < cs || (os == cs && oj < cj)))) {
                cx = ox; cs = os; cj = oj;
            }
        }
        if ((k & 63) == 0) { s_rx[k>>6] = cx; s_rs[k>>6] = cs; s_rj[k>>6] = cj; }
        __syncthreads();
        if (k == 0) {
            cx = s_rx[0]; cs = s_rs[0]; cj = s_rj[0];
            for (int i = 1; i < 4; i++) {
                if (s_rx[i] < cx || (s_rx[i] == cx && (s_rs[i] < cs ||
                    (s_rs[i] == cs && s_rj[i] < cj)))) {
                    cx = s_rx[i]; cs = s_rs[i]; cj = s_rj[i];
                }
            }
            s_bx = cx;
            s_bj = (cx == DBL_MAX) ? -1 : cj;
        }
        __syncthreads();
        if (s_bj < 0) break;                 // no line ever overtakes: done
        if (k == 0) {
            g_breaks[c*NK + m] = s_bx;
            g_win[c*NK + m]    = s_bj;
        }
        cur = s_bj;
        m++;
    }
    if (k == 0) g_m[c] = m;
}

// ---------------------------------------------------------------------------
// Kernel 2: per-row binary search on the envelope + outputs
// ---------------------------------------------------------------------------
__global__ __launch_bounds__(TPB) void vq_main(
    const float* __restrict__ x,
    const float* __restrict__ w_pre,
    const float* __restrict__ b_pre,
    const float* __restrict__ codebook,
    const float* __restrict__ w_after,
    const float* __restrict__ b_after,
    const double* __restrict__ g_breaks,
    const int* __restrict__ g_win,
    const int* __restrict__ g_m,
    float* __restrict__ out,
    double* __restrict__ partial)
{
    __shared__ double2 s_PS[NK];      // {P[k], S[k]}  (for kl distance)
    __shared__ double  s_R[NK];       // recon value per code (this block's c)
    __shared__ float   s_cb[NK][NQ];  // raw codebook rows
    __shared__ double  s_breaks[NK];
    __shared__ int     s_win[NK];
    __shared__ double  s_part[TPB/64];

    const int tid = threadIdx.x;
    const int gid = blockIdx.x * TPB + tid;
    const int c  = (gid >> 10) & 63;   // block-uniform
    const int b  = gid >> 16;          // block-uniform
    const int hw = gid & 1023;

    double wp[NQ], bp[NQ], wa[NQ];
    #pragma unroll
    for (int q = 0; q < NQ; q++) {
        wp[q] = (double)w_pre[c*NQ + q];
        bp[q] = (double)b_pre[c*NQ + q];
        wa[q] = (double)w_after[c*NQ + q];
    }
    const double ba = (double)b_after[c];

    // stage per-code tables; thread tid handles code k = tid
    {
        const int k = tid;
        double c2 = 0.0, A = 0.0, Bv = 0.0, R = ba;
        #pragma unroll
        for (int q = 0; q < NQ; q++) {
            float cf = codebook[k*NQ + q];
            s_cb[k][q] = cf;
            double cv = (double)cf;
            c2 = fma(cv, cv, c2);
            A  = fma(wp[q], cv, A);
            Bv = fma(bp[q], cv, Bv);
            R  = fma(wa[q], cv, R);
        }
        s_PS[k] = make_double2(c2 - 2.0*Bv, -2.0*A);
        s_R[k]  = R;
    }
    const int m = g_m[c];              // block-uniform
    if (tid < m) {
        s_win[tid]    = g_win[c*NK + tid];
        s_breaks[tid] = (tid == 0) ? -DBL_MAX : g_breaks[c*NK + tid];
    }
    __syncthreads();

    const double xv = (double)x[gid];

    // binary search: largest seg i with s_breaks[i] <= xv
    int lo = 0, hi = m - 1;
    while (lo < hi) {
        int mid = (lo + hi + 1) >> 1;
        if (s_breaks[mid] <= xv) lo = mid; else hi = mid - 1;
    }
    const int best = s_win[lo];
    const double2 ps = s_PS[best];
    const double bd = fma(xv, ps.y, ps.x);   // P[best] + x*S[best]

    // outputs
    const int bq_base = BIT_OFF + (b*512 + c*8)*1024 + hw;
    #pragma unroll
    for (int q = 0; q < NQ; q++)
        out[bq_base + q*1024] = s_cb[best][q];   // bit_out == codebook[best]
    out[REC_OFF + gid] = (float)s_R[best];

    // kl partial: full dist = bd + (x^2*sw2 + 2x*swb + sb2)
    double sw2 = 0.0, swb = 0.0, sb2 = 0.0;
    #pragma unroll
    for (int q = 0; q < NQ; q++) {
        sw2 = fma(wp[q], wp[q], sw2);
        swb = fma(wp[q], bp[q], swb);
        sb2 = fma(bp[q], bp[q], sb2);
    }
    double ksum = bd + fma(xv, fma(xv, sw2, 2.0*swb), sb2);

    #pragma unroll
    for (int off = 32; off; off >>= 1)
        ksum += __shfl_down(ksum, off, 64);
    if ((tid & 63) == 0) s_part[tid >> 6] = ksum;
    __syncthreads();
    if (tid == 0)
        partial[blockIdx.x] = s_part[0] + s_part[1] + s_part[2] + s_part[3];
}

__global__ __launch_bounds__(TPB) void vq_fin(
    const double* __restrict__ partial,
    float* __restrict__ out)
{
    double s = 0.0;
    for (int i = threadIdx.x; i < NBLK; i += TPB) s += partial[i];
    #pragma unroll
    for (int off = 32; off; off >>= 1)
        s += __shfl_down(s, off, 64);
    __shared__ double sp[TPB/64];
    if ((threadIdx.x & 63) == 0) sp[threadIdx.x >> 6] = s;
    __syncthreads();
    if (threadIdx.x == 0) {
        double m = (sp[0] + sp[1] + sp[2] + sp[3]) / (double)(NROWS * NQ);
        out[0] = (float)(1.25 * m);
    }
}

extern "C" void kernel_launch(void* const* d_in, const int* in_sizes, int n_in,
                              void* d_out, int out_size, void* d_ws, size_t ws_size,
                              hipStream_t stream) {
    const float* x        = (const float*)d_in[0];
    const float* w_pre    = (const float*)d_in[1];
    const float* b_pre    = (const float*)d_in[2];
    const float* codebook = (const float*)d_in[3];
    const float* w_after  = (const float*)d_in[4];
    const float* b_after  = (const float*)d_in[5];
    float* out = (float*)d_out;

    double* breaks = WS_BREAKS(d_ws);
    int*    win    = WS_WIN(d_ws);
    int*    mcnt   = WS_M(d_ws);
    double* part   = WS_PART(d_ws);

    vq_envelope<<<NC, TPB, 0, stream>>>(w_pre, b_pre, codebook, breaks, win, mcnt);
    vq_main<<<NBLK, TPB, 0, stream>>>(x, w_pre, b_pre, codebook, w_after, b_after,
                                      breaks, win, mcnt, out, part);
    vq_fin<<<1, TPB, 0, stream>>>(part, out);
}